// Round 1
// baseline (279.507 us; speedup 1.0000x reference)
//
#include <hip/hip_runtime.h>
#include <hip/hip_bf16.h>
#include <math.h>

#define BS 1024
#define D 128
#define NP 100000
#define CW 128                       // proxy cols per block/chunk
#define NCHUNK ((NP + CW - 1) / CW)  // 782
#define NITER (BS / 128)             // 8 row-tiles of 128

typedef float f32x4 __attribute__((ext_vector_type(4)));
typedef __bf16 bf16x8 __attribute__((ext_vector_type(8)));

#define LOG2E 1.44269504088896340736f

static __device__ __forceinline__ unsigned short f2bf(float x) {
    unsigned int u = __float_as_uint(x);
    unsigned int r = (u + 0x7fffu + ((u >> 16) & 1u)) >> 16;  // RNE
    return (unsigned short)r;
}

// ---------------- kernel 1: normalize batch -> bf16 A, and d_pos -------------
// one wave per row; 256 blocks x 256 threads
__global__ __launch_bounds__(256) void prep_kernel(
    const float* __restrict__ batch, const float* __restrict__ proxies,
    const int* __restrict__ labels, unsigned short* __restrict__ A,
    float* __restrict__ d_pos)
{
    int wave = threadIdx.x >> 6;
    int lane = threadIdx.x & 63;
    int row  = blockIdx.x * 4 + wave;   // 0..1023

    float2 bv = *(const float2*)(batch + (size_t)row * D + lane * 2);
    float ss = bv.x * bv.x + bv.y * bv.y;
    #pragma unroll
    for (int m = 1; m < 64; m <<= 1) ss += __shfl_xor(ss, m, 64);
    float sb = 3.0f / fmaxf(sqrtf(ss), 1e-12f);
    float ax = bv.x * sb, ay = bv.y * sb;

    ushort2 pk; pk.x = f2bf(ax); pk.y = f2bf(ay);
    *(ushort2*)(A + (size_t)row * D + lane * 2) = pk;

    // d_pos in fp32: 18 - 2 * (b . p_label)
    int lab = labels[row];
    float2 pv = *(const float2*)(proxies + (size_t)lab * D + lane * 2);
    float ps = pv.x * pv.x + pv.y * pv.y;
    #pragma unroll
    for (int m = 1; m < 64; m <<= 1) ps += __shfl_xor(ps, m, 64);
    float sp = 3.0f / fmaxf(sqrtf(ps), 1e-12f);
    float dot = ax * (pv.x * sp) + ay * (pv.y * sp);
    #pragma unroll
    for (int m = 1; m < 64; m <<= 1) dot += __shfl_xor(dot, m, 64);
    if (lane == 0) d_pos[row] = 18.0f - 2.0f * dot;
}

// ---------------- kernel 2: fused GEMM + exp row-sums ------------------------
// grid = NCHUNK blocks, 256 threads (4 waves). Each block: 128 proxies
// (normalized fp32->bf16 into swizzled LDS once), loop over 8 row-tiles of 128.
// wave w owns rows [tile*128 + w*32, +32) x all 128 cols -> no cross-wave sums.
__global__ __launch_bounds__(256) void main_kernel(
    const float* __restrict__ proxies,
    const unsigned short* __restrict__ A,   // bf16 bits [BS][D]
    float* __restrict__ partials)           // [NCHUNK][BS]
{
    __shared__ unsigned char Blds[CW * 256];  // 128 rows x 256B, XOR-swizzled

    int chunk = blockIdx.x;
    int cbase = chunk * CW;
    int wave = threadIdx.x >> 6;
    int lane = threadIdx.x & 63;
    int quad = lane >> 4;
    int l15  = lane & 15;

    // ---- stage B chunk: wave handles rows [wave*32, wave*32+32) -------------
    for (int i = 0; i < 32; ++i) {
        int r = wave * 32 + i;
        int pidx = cbase + r;
        float2 v = make_float2(0.0f, 0.0f);
        if (pidx < NP) v = *(const float2*)(proxies + (size_t)pidx * D + lane * 2);
        float ss = v.x * v.x + v.y * v.y;
        #pragma unroll
        for (int m = 1; m < 64; m <<= 1) ss += __shfl_xor(ss, m, 64);
        float sc = 3.0f / fmaxf(sqrtf(ss), 1e-12f);
        if (pidx >= NP) sc = 0.0f;
        unsigned int packed = ((unsigned int)f2bf(v.y * sc) << 16) | f2bf(v.x * sc);
        // logical dword position within row = lane (64 dwords); 16B chunk = lane>>2
        int c16 = (lane >> 2) ^ (r & 15);
        *(unsigned int*)(Blds + r * 256 + c16 * 16 + (lane & 3) * 4) = packed;
    }
    __syncthreads();

    const float c1 = 2.0f * LOG2E;
    const float c0 = -18.0f * LOG2E;

    for (int it = 0; it < NITER; ++it) {
        int rowbase = it * 128 + wave * 32;

        f32x4 acc[2][8];
        #pragma unroll
        for (int fr = 0; fr < 2; ++fr)
            #pragma unroll
            for (int fc = 0; fc < 8; ++fc)
                acc[fr][fc] = (f32x4){0.f, 0.f, 0.f, 0.f};

        #pragma unroll
        for (int kk = 0; kk < 4; ++kk) {
            bf16x8 a[2], b[8];
            #pragma unroll
            for (int fr = 0; fr < 2; ++fr) {
                int grow = rowbase + fr * 16 + l15;
                a[fr] = *(const bf16x8*)(A + (size_t)grow * D + kk * 32 + quad * 8);
            }
            #pragma unroll
            for (int fc = 0; fc < 8; ++fc) {
                int br = fc * 16 + l15;
                int c16 = (kk * 4 + quad) ^ (br & 15);
                b[fc] = *(const bf16x8*)(Blds + br * 256 + c16 * 16);
            }
            #pragma unroll
            for (int fr = 0; fr < 2; ++fr)
                #pragma unroll
                for (int fc = 0; fc < 8; ++fc)
                    acc[fr][fc] = __builtin_amdgcn_mfma_f32_16x16x32_bf16(
                        a[fr], b[fc], acc[fr][fc], 0, 0, 0);
        }

        // ---- epilogue: e = exp(2s - 18), row-sum over this chunk's 128 cols -
        #pragma unroll
        for (int fr = 0; fr < 2; ++fr) {
            #pragma unroll
            for (int reg = 0; reg < 4; ++reg) {
                float rs = 0.0f;
                #pragma unroll
                for (int fc = 0; fc < 8; ++fc) {
                    int gcol = cbase + fc * 16 + l15;
                    float s = acc[fr][fc][reg];
                    float e = exp2f(fmaf(s, c1, c0));
                    rs += (gcol < NP) ? e : 0.0f;
                }
                // sum across the 16 lanes (low 4 lane bits) sharing a row
                #pragma unroll
                for (int m = 1; m < 16; m <<= 1) rs += __shfl_xor(rs, m, 64);
                if (l15 == 0) {
                    int grow = rowbase + fr * 16 + quad * 4 + reg;
                    partials[(size_t)chunk * BS + grow] = rs;
                }
            }
        }
    }
}

// ---------------- kernel 3: reduce partials over chunk slices ----------------
#define NSLICE 8
__global__ __launch_bounds__(256) void rowsum_kernel(
    const float* __restrict__ partials, float* __restrict__ partial2)
{
    int r  = (blockIdx.x & 3) * 256 + threadIdx.x;  // row 0..1023
    int sl = blockIdx.x >> 2;                       // slice 0..7
    float s = 0.0f;
    for (int c = sl; c < NCHUNK; c += NSLICE)
        s += partials[(size_t)c * BS + r];
    partial2[sl * BS + r] = s;
}

// ---------------- kernel 4: final lse + mean ---------------------------------
__global__ __launch_bounds__(1024) void final_kernel(
    const float* __restrict__ partial2, const float* __restrict__ d_pos,
    float* __restrict__ out)
{
    int r = threadIdx.x;  // 1024 threads
    float tot = 0.0f;
    #pragma unroll
    for (int sl = 0; sl < NSLICE; ++sl) tot += partial2[sl * BS + r];
    float dp  = d_pos[r];
    float neg = tot - __expf(-dp);            // exclude own-class column
    float val = dp + __logf(fmaxf(neg, 1e-37f));

    #pragma unroll
    for (int m = 1; m < 64; m <<= 1) val += __shfl_xor(val, m, 64);
    __shared__ float red[16];
    if ((threadIdx.x & 63) == 0) red[threadIdx.x >> 6] = val;
    __syncthreads();
    if (threadIdx.x < 16) {
        float v = red[threadIdx.x];
        #pragma unroll
        for (int m = 1; m < 16; m <<= 1) v += __shfl_xor(v, m, 64);
        if (threadIdx.x == 0) out[0] = v * (1.0f / 1024.0f);
    }
}

extern "C" void kernel_launch(void* const* d_in, const int* in_sizes, int n_in,
                              void* d_out, int out_size, void* d_ws, size_t ws_size,
                              hipStream_t stream) {
    const float* batch   = (const float*)d_in[0];
    const float* proxies = (const float*)d_in[1];
    const int*   labels  = (const int*)d_in[2];
    float* out = (float*)d_out;

    char* ws = (char*)d_ws;
    unsigned short* A  = (unsigned short*)ws;                       // 256 KB
    float* d_pos       = (float*)(ws + 262144);                     // 4 KB
    float* partials    = (float*)(ws + 266240);                     // 3.203 MB
    float* partial2    = (float*)(ws + 266240 + (size_t)NCHUNK * BS * 4);

    prep_kernel<<<256, 256, 0, stream>>>(batch, proxies, labels, A, d_pos);
    main_kernel<<<NCHUNK, 256, 0, stream>>>(proxies, A, partials);
    rowsum_kernel<<<32, 256, 0, stream>>>(partials, partial2);
    final_kernel<<<1, 1024, 0, stream>>>(partial2, d_pos, out);
}

// Round 2
// 264.437 us; speedup vs baseline: 1.0570x; 1.0570x over previous
//
#include <hip/hip_runtime.h>
#include <hip/hip_bf16.h>
#include <math.h>

#define BS 1024
#define D 128
#define NP 100000
#define PROWS 100032              // padded to multiple of 64 (32 zero rows)
#define CH 64                     // proxies per chunk/block
#define NCH (PROWS / CH)          // 1563
#define PBLK (PROWS / 8)          // 12504 proxy-norm blocks
#define LOG2E 1.44269504088896340736f

typedef float f32x4 __attribute__((ext_vector_type(4)));
typedef __bf16 bf16x8 __attribute__((ext_vector_type(8)));

static __device__ __forceinline__ unsigned short f2bf(float x) {
    unsigned int u = __float_as_uint(x);
    return (unsigned short)((u + 0x7fffu + ((u >> 16) & 1u)) >> 16);  // RNE
}

// ---------- kernel 1: normalize proxies -> bf16 P (zero-padded), batch -> A,
// ---------- and d_pos.  2 rows per wave, float4 per lane (32 lanes/row).
__global__ __launch_bounds__(256) void norm_kernel(
    const float* __restrict__ batch, const float* __restrict__ proxies,
    const int* __restrict__ labels, unsigned short* __restrict__ P,
    unsigned short* __restrict__ A, float* __restrict__ d_pos)
{
    int wave = threadIdx.x >> 6, lane = threadIdx.x & 63;
    int sub = lane >> 5, c = lane & 31;
    if (blockIdx.x < PBLK) {
        int row = blockIdx.x * 8 + wave * 2 + sub;
        float4 v = make_float4(0.f, 0.f, 0.f, 0.f);
        if (row < NP) v = *(const float4*)(proxies + (size_t)row * D + c * 4);
        float ss = v.x*v.x + v.y*v.y + v.z*v.z + v.w*v.w;
        #pragma unroll
        for (int m = 1; m < 32; m <<= 1) ss += __shfl_xor(ss, m, 64);
        float sc = 3.0f / fmaxf(sqrtf(ss), 1e-12f);
        ushort4 pk;
        pk.x = f2bf(v.x*sc); pk.y = f2bf(v.y*sc);
        pk.z = f2bf(v.z*sc); pk.w = f2bf(v.w*sc);
        *(ushort4*)(P + (size_t)row * D + c * 4) = pk;   // pad rows -> zeros
    } else {
        int row = (blockIdx.x - PBLK) * 8 + wave * 2 + sub;   // 0..1023
        float4 v = *(const float4*)(batch + (size_t)row * D + c * 4);
        float ss = v.x*v.x + v.y*v.y + v.z*v.z + v.w*v.w;
        #pragma unroll
        for (int m = 1; m < 32; m <<= 1) ss += __shfl_xor(ss, m, 64);
        float sc = 3.0f / fmaxf(sqrtf(ss), 1e-12f);
        ushort4 pk;
        pk.x = f2bf(v.x*sc); pk.y = f2bf(v.y*sc);
        pk.z = f2bf(v.z*sc); pk.w = f2bf(v.w*sc);
        *(ushort4*)(A + (size_t)row * D + c * 4) = pk;
        // d_pos in fp32
        int lab = labels[row];
        float4 p4 = *(const float4*)(proxies + (size_t)lab * D + c * 4);
        float ps = p4.x*p4.x + p4.y*p4.y + p4.z*p4.z + p4.w*p4.w;
        #pragma unroll
        for (int m = 1; m < 32; m <<= 1) ps += __shfl_xor(ps, m, 64);
        float psc = 3.0f / fmaxf(sqrtf(ps), 1e-12f);
        float dt = (v.x*sc)*(p4.x*psc) + (v.y*sc)*(p4.y*psc)
                 + (v.z*sc)*(p4.z*psc) + (v.w*sc)*(p4.w*psc);
        #pragma unroll
        for (int m = 1; m < 32; m <<= 1) dt += __shfl_xor(dt, m, 64);
        if (c == 0) d_pos[row] = 18.0f - 2.0f * dt;
    }
}

// ---------- kernel 2: GEMM + exp, proxies in M (A-op), batch in N (B-op).
// Per block: 64 proxies register-cached (via LDS, XOR-swizzled); each wave
// handles 16 batch groups of 16 rows; row-sum over proxies is in-lane + 2
// shuffles at group end. Writes partials[chunk][1024].
__global__ __launch_bounds__(256, 3) void main_kernel(
    const unsigned short* __restrict__ P,
    const unsigned short* __restrict__ Abat,
    float* __restrict__ partials)
{
    __shared__ unsigned short Plds[CH * D];   // 16 KB
    const int tid = threadIdx.x;
    const int lane = tid & 63;
    const int wave = tid >> 6, quad = lane >> 4, l15 = lane & 15;
    const int chunk = blockIdx.x;

    // stage P chunk: logical (row, cl16B) -> phys chunk16 = cl ^ (row&15)
    #pragma unroll
    for (int p = 0; p < 4; ++p) {
        int S = p * 256 + tid;
        int row = S >> 4, cl = S & 15;
        bf16x8 v = *(const bf16x8*)(P + (size_t)(chunk * CH + row) * D + cl * 8);
        *(bf16x8*)((char*)Plds + row * 256 + (((cl ^ (row & 15))) << 4)) = v;
    }
    __syncthreads();

    // register-cache A-frags (proxies): 4 Mtiles x 4 kk
    bf16x8 Af[4][4];
    #pragma unroll
    for (int m = 0; m < 4; ++m)
        #pragma unroll
        for (int kk = 0; kk < 4; ++kk) {
            int row = m * 16 + l15;
            int cl = kk * 4 + quad;
            Af[m][kk] = *(const bf16x8*)((const char*)Plds + row * 256 + ((cl ^ l15) << 4));
        }

    const float c1 = 2.0f * LOG2E, c0 = -18.0f * LOG2E;
    const int row0 = wave * 256;   // this wave's 256 batch rows (16 groups)
    const unsigned short* ab = Abat + (size_t)(row0 + l15) * D + quad * 8;

    bf16x8 Bf[2][4];
    #pragma unroll
    for (int kk = 0; kk < 4; ++kk) Bf[0][kk] = *(const bf16x8*)(ab + kk * 32);

    #pragma unroll
    for (int g = 0; g < 16; ++g) {
        if (g < 15) {   // prefetch next group's B-frags
            #pragma unroll
            for (int kk = 0; kk < 4; ++kk)
                Bf[(g + 1) & 1][kk] = *(const bf16x8*)(ab + (size_t)(g + 1) * 16 * D + kk * 32);
        }
        f32x4 acc[4];
        #pragma unroll
        for (int m = 0; m < 4; ++m) acc[m] = (f32x4){0.f, 0.f, 0.f, 0.f};
        #pragma unroll
        for (int kk = 0; kk < 4; ++kk)
            #pragma unroll
            for (int m = 0; m < 4; ++m)
                acc[m] = __builtin_amdgcn_mfma_f32_16x16x32_bf16(
                    Af[m][kk], Bf[g & 1][kk], acc[m], 0, 0, 0);
        // epilogue: lane's batch col = row0+g*16+l15; 16 proxies in-lane
        float t[4];
        #pragma unroll
        for (int m = 0; m < 4; ++m) {
            float e0 = exp2f(fmaf(acc[m][0], c1, c0));
            float e1 = exp2f(fmaf(acc[m][1], c1, c0));
            float e2 = exp2f(fmaf(acc[m][2], c1, c0));
            float e3 = exp2f(fmaf(acc[m][3], c1, c0));
            t[m] = (e0 + e1) + (e2 + e3);
        }
        float rs = (t[0] + t[1]) + (t[2] + t[3]);
        rs += __shfl_xor(rs, 16, 64);   // combine quads (proxy rows)
        rs += __shfl_xor(rs, 32, 64);
        if (quad == 0)
            partials[(size_t)chunk * BS + row0 + g * 16 + l15] = rs;
    }
}

// ---------- kernel 3: per-row total + lse + mean (16 blocks, atomicAdd out)
__global__ __launch_bounds__(256) void final_kernel(
    const float* __restrict__ partials, const float* __restrict__ d_pos,
    float* __restrict__ out)
{
    __shared__ float red[4][64];
    int sub = threadIdx.x >> 6;        // 0..3
    int l = threadIdx.x & 63;
    int rowb = blockIdx.x * 64;        // 16 blocks x 64 rows
    float s = 0.f;
    for (int ci = sub; ci < NCH; ci += 4)
        s += partials[(size_t)ci * BS + rowb + l];
    red[sub][l] = s;
    __syncthreads();
    if (sub == 0) {
        float tot = (red[0][l] + red[1][l]) + (red[2][l] + red[3][l]);
        float dp = d_pos[rowb + l];
        const float PADC = 32.0f * exp2f(-18.0f * LOG2E);  // zero-pad rows
        float neg = tot - expf(-dp) - PADC;                // drop own column
        float val = dp + logf(fmaxf(neg, 1e-37f));
        #pragma unroll
        for (int m = 1; m < 64; m <<= 1) val += __shfl_xor(val, m, 64);
        if (l == 0) atomicAdd(out, val * (1.0f / 1024.0f));
    }
}

extern "C" void kernel_launch(void* const* d_in, const int* in_sizes, int n_in,
                              void* d_out, int out_size, void* d_ws, size_t ws_size,
                              hipStream_t stream) {
    const float* batch   = (const float*)d_in[0];
    const float* proxies = (const float*)d_in[1];
    const int*   labels  = (const int*)d_in[2];
    float* out = (float*)d_out;

    char* ws = (char*)d_ws;
    unsigned short* P  = (unsigned short*)ws;                    // 25,608,192 B
    unsigned short* A  = (unsigned short*)(ws + 25608192);       //    262,144 B
    float* d_pos       = (float*)(ws + 25870336);                //      4,096 B
    float* partials    = (float*)(ws + 25874432);                //  6,402,048 B

    hipMemsetAsync(d_out, 0, sizeof(float), stream);
    norm_kernel<<<PBLK + BS / 8, 256, 0, stream>>>(batch, proxies, labels, P, A, d_pos);
    main_kernel<<<NCH, 256, 0, stream>>>(P, A, partials);
    final_kernel<<<16, 256, 0, stream>>>(partials, d_pos, out);
}

// Round 3
// 161.095 us; speedup vs baseline: 1.7350x; 1.6415x over previous
//
#include <hip/hip_runtime.h>
#include <hip/hip_bf16.h>
#include <math.h>

#define BS 1024
#define D 128
#define NP 100000
#define PROWS 100032              // padded to multiple of 64 (32 zero rows)
#define CH 64                     // proxies per chunk/block
#define NCH (PROWS / CH)          // 1563
#define PBLK (PROWS / 8)          // 12504 proxy-norm blocks
#define NSL 64                    // reduction slices
#define LOG2E 1.44269504088896340736f

typedef float f32x4 __attribute__((ext_vector_type(4)));
typedef __bf16 bf16x8 __attribute__((ext_vector_type(8)));

static __device__ __forceinline__ unsigned short f2bf(float x) {
    unsigned int u = __float_as_uint(x);
    return (unsigned short)((u + 0x7fffu + ((u >> 16) & 1u)) >> 16);  // RNE
}

// ---------- kernel 1: normalize proxies -> bf16 P (zero-padded), batch -> A,
// ---------- and d_pos.  2 rows per wave, float4 per lane (32 lanes/row).
__global__ __launch_bounds__(256) void norm_kernel(
    const float* __restrict__ batch, const float* __restrict__ proxies,
    const int* __restrict__ labels, unsigned short* __restrict__ P,
    unsigned short* __restrict__ A, float* __restrict__ d_pos)
{
    int wave = threadIdx.x >> 6, lane = threadIdx.x & 63;
    int sub = lane >> 5, c = lane & 31;
    if (blockIdx.x < PBLK) {
        int row = blockIdx.x * 8 + wave * 2 + sub;
        float4 v = make_float4(0.f, 0.f, 0.f, 0.f);
        if (row < NP) v = *(const float4*)(proxies + (size_t)row * D + c * 4);
        float ss = v.x*v.x + v.y*v.y + v.z*v.z + v.w*v.w;
        #pragma unroll
        for (int m = 1; m < 32; m <<= 1) ss += __shfl_xor(ss, m, 64);
        float sc = 3.0f / fmaxf(sqrtf(ss), 1e-12f);
        ushort4 pk;
        pk.x = f2bf(v.x*sc); pk.y = f2bf(v.y*sc);
        pk.z = f2bf(v.z*sc); pk.w = f2bf(v.w*sc);
        *(ushort4*)(P + (size_t)row * D + c * 4) = pk;   // pad rows -> zeros
    } else {
        int row = (blockIdx.x - PBLK) * 8 + wave * 2 + sub;   // 0..1023
        float4 v = *(const float4*)(batch + (size_t)row * D + c * 4);
        float ss = v.x*v.x + v.y*v.y + v.z*v.z + v.w*v.w;
        #pragma unroll
        for (int m = 1; m < 32; m <<= 1) ss += __shfl_xor(ss, m, 64);
        float sc = 3.0f / fmaxf(sqrtf(ss), 1e-12f);
        ushort4 pk;
        pk.x = f2bf(v.x*sc); pk.y = f2bf(v.y*sc);
        pk.z = f2bf(v.z*sc); pk.w = f2bf(v.w*sc);
        *(ushort4*)(A + (size_t)row * D + c * 4) = pk;
        // d_pos in fp32
        int lab = labels[row];
        float4 p4 = *(const float4*)(proxies + (size_t)lab * D + c * 4);
        float ps = p4.x*p4.x + p4.y*p4.y + p4.z*p4.z + p4.w*p4.w;
        #pragma unroll
        for (int m = 1; m < 32; m <<= 1) ps += __shfl_xor(ps, m, 64);
        float psc = 3.0f / fmaxf(sqrtf(ps), 1e-12f);
        float dt = (v.x*sc)*(p4.x*psc) + (v.y*sc)*(p4.y*psc)
                 + (v.z*sc)*(p4.z*psc) + (v.w*sc)*(p4.w*psc);
        #pragma unroll
        for (int m = 1; m < 32; m <<= 1) dt += __shfl_xor(dt, m, 64);
        if (c == 0) d_pos[row] = 18.0f - 2.0f * dt;
    }
}

// ---------- kernel 2: GEMM + exp, proxies in M (A-op), batch in N (B-op).
__global__ __launch_bounds__(256, 3) void main_kernel(
    const unsigned short* __restrict__ P,
    const unsigned short* __restrict__ Abat,
    float* __restrict__ partials)
{
    __shared__ unsigned short Plds[CH * D];   // 16 KB
    const int tid = threadIdx.x;
    const int lane = tid & 63;
    const int wave = tid >> 6, quad = lane >> 4, l15 = lane & 15;
    const int chunk = blockIdx.x;

    // stage P chunk: logical (row, cl16B) -> phys chunk16 = cl ^ (row&15)
    #pragma unroll
    for (int p = 0; p < 4; ++p) {
        int S = p * 256 + tid;
        int row = S >> 4, cl = S & 15;
        bf16x8 v = *(const bf16x8*)(P + (size_t)(chunk * CH + row) * D + cl * 8);
        *(bf16x8*)((char*)Plds + row * 256 + (((cl ^ (row & 15))) << 4)) = v;
    }
    __syncthreads();

    // register-cache A-frags (proxies): 4 Mtiles x 4 kk
    bf16x8 Af[4][4];
    #pragma unroll
    for (int m = 0; m < 4; ++m)
        #pragma unroll
        for (int kk = 0; kk < 4; ++kk) {
            int row = m * 16 + l15;
            int cl = kk * 4 + quad;
            Af[m][kk] = *(const bf16x8*)((const char*)Plds + row * 256 + ((cl ^ l15) << 4));
        }

    const float c1 = 2.0f * LOG2E, c0 = -18.0f * LOG2E;
    const int row0 = wave * 256;   // this wave's 256 batch rows (16 groups)
    const unsigned short* ab = Abat + (size_t)(row0 + l15) * D + quad * 8;

    bf16x8 Bf[2][4];
    #pragma unroll
    for (int kk = 0; kk < 4; ++kk) Bf[0][kk] = *(const bf16x8*)(ab + kk * 32);

    #pragma unroll
    for (int g = 0; g < 16; ++g) {
        if (g < 15) {   // prefetch next group's B-frags
            #pragma unroll
            for (int kk = 0; kk < 4; ++kk)
                Bf[(g + 1) & 1][kk] = *(const bf16x8*)(ab + (size_t)(g + 1) * 16 * D + kk * 32);
        }
        f32x4 acc[4];
        #pragma unroll
        for (int m = 0; m < 4; ++m) acc[m] = (f32x4){0.f, 0.f, 0.f, 0.f};
        #pragma unroll
        for (int kk = 0; kk < 4; ++kk)
            #pragma unroll
            for (int m = 0; m < 4; ++m)
                acc[m] = __builtin_amdgcn_mfma_f32_16x16x32_bf16(
                    Af[m][kk], Bf[g & 1][kk], acc[m], 0, 0, 0);
        // epilogue: lane's batch col = row0+g*16+l15; 16 proxies in-lane
        float t[4];
        #pragma unroll
        for (int m = 0; m < 4; ++m) {
            float e0 = exp2f(fmaf(acc[m][0], c1, c0));
            float e1 = exp2f(fmaf(acc[m][1], c1, c0));
            float e2 = exp2f(fmaf(acc[m][2], c1, c0));
            float e3 = exp2f(fmaf(acc[m][3], c1, c0));
            t[m] = (e0 + e1) + (e2 + e3);
        }
        float rs = (t[0] + t[1]) + (t[2] + t[3]);
        rs += __shfl_xor(rs, 16, 64);   // combine quads (proxy rows)
        rs += __shfl_xor(rs, 32, 64);
        if (quad == 0)
            partials[(size_t)chunk * BS + row0 + g * 16 + l15] = rs;
    }
}

// ---------- kernel 3a: parallel chunk reduction: 256 blocks --------------
// block = (slice sl = bid>>2, rowgroup rg = bid&3); thread -> one row.
__global__ __launch_bounds__(256) void reduce1_kernel(
    const float* __restrict__ partials, float* __restrict__ partial2)
{
    int sl  = blockIdx.x >> 2;                    // 0..63
    int row = (blockIdx.x & 3) * 256 + threadIdx.x;
    float s = 0.f;
    for (int ci = sl; ci < NCH; ci += NSL)
        s += partials[(size_t)ci * BS + row];
    partial2[(size_t)sl * BS + row] = s;
}

// ---------- kernel 3b: final lse + mean (4 blocks, atomicAdd out) --------
__global__ __launch_bounds__(256) void final_kernel(
    const float* __restrict__ partial2, const float* __restrict__ d_pos,
    float* __restrict__ out)
{
    int row = blockIdx.x * 256 + threadIdx.x;
    float tot = 0.f;
    #pragma unroll 8
    for (int sl = 0; sl < NSL; ++sl)
        tot += partial2[(size_t)sl * BS + row];
    float dp = d_pos[row];
    const float PADC = 32.0f * exp2f(-18.0f * LOG2E);  // zero-pad rows
    float neg = tot - expf(-dp) - PADC;                // drop own column
    float val = dp + logf(fmaxf(neg, 1e-37f));
    #pragma unroll
    for (int m = 1; m < 64; m <<= 1) val += __shfl_xor(val, m, 64);
    __shared__ float red[4];
    if ((threadIdx.x & 63) == 0) red[threadIdx.x >> 6] = val;
    __syncthreads();
    if (threadIdx.x == 0) {
        float v = (red[0] + red[1]) + (red[2] + red[3]);
        atomicAdd(out, v * (1.0f / 1024.0f));
    }
}

extern "C" void kernel_launch(void* const* d_in, const int* in_sizes, int n_in,
                              void* d_out, int out_size, void* d_ws, size_t ws_size,
                              hipStream_t stream) {
    const float* batch   = (const float*)d_in[0];
    const float* proxies = (const float*)d_in[1];
    const int*   labels  = (const int*)d_in[2];
    float* out = (float*)d_out;

    char* ws = (char*)d_ws;
    unsigned short* P  = (unsigned short*)ws;                    // 25,608,192 B
    unsigned short* A  = (unsigned short*)(ws + 25608192);       //    262,144 B
    float* d_pos       = (float*)(ws + 25870336);                //      4,096 B
    float* partials    = (float*)(ws + 25874432);                //  6,402,048 B
    float* partial2    = (float*)(ws + 32276480);                //    262,144 B

    hipMemsetAsync(d_out, 0, sizeof(float), stream);
    norm_kernel<<<PBLK + BS / 8, 256, 0, stream>>>(batch, proxies, labels, P, A, d_pos);
    main_kernel<<<NCH, 256, 0, stream>>>(P, A, partials);
    reduce1_kernel<<<NSL * 4, 256, 0, stream>>>(partials, partial2);
    final_kernel<<<4, 256, 0, stream>>>(partial2, d_pos, out);
}